// Round 12
// baseline (128388.672 us; speedup 1.0000x reference)
//
#include <hip/hip_runtime.h>
#include <math.h>

#define NB    2048
#define FIN   32
#define HH    512
#define G4    2048           // 4*H
#define BNE   64
#define OUTD  8
#define SEQL  128
#define LOOK  32
#define TOT   (SEQL + LOOK)
#define TB    16             // samples per workgroup  (128 WGs total)
#define NTHR  1024

__device__ __forceinline__ float sigf(float v) { return 1.0f / (1.0f + expf(-v)); }

// One k-slice (r6 verbatim): gate accum A[i] (float2 over unit-pair) += w * state[s4+i]
#define GMAC4(A, W)                                                     \
  { A[0].x = fmaf((W).x, hv.x, A[0].x); A[0].y = fmaf((W).y, hv.x, A[0].y); \
    A[1].x = fmaf((W).x, hv.y, A[1].x); A[1].y = fmaf((W).y, hv.y, A[1].y); \
    A[2].x = fmaf((W).x, hv.z, A[2].x); A[2].y = fmaf((W).y, hv.z, A[2].y); \
    A[3].x = fmaf((W).x, hv.w, A[3].x); A[3].y = fmaf((W).y, hv.w, A[3].y); }

__global__ __launch_bounds__(NTHR)
void fused_rnn(const float* __restrict__ x,
               const float* __restrict__ Wih0, const float* __restrict__ Whh0,
               const float* __restrict__ bih0, const float* __restrict__ bhh0,
               const float* __restrict__ Wih1, const float* __restrict__ Whh1,
               const float* __restrict__ bih1, const float* __restrict__ bhh1,
               const float* __restrict__ We,   const float* __restrict__ be,
               const float* __restrict__ Wd,   const float* __restrict__ bd,
               const float* __restrict__ Wf,   const float* __restrict__ bf,
               float* __restrict__ out)
{
  // states [unit][sample]: fixed-k access is a wave-uniform b128 broadcast
  __shared__ float sh0[HH][TB], sc0[HH][TB], sh1[HH][TB], sc1[HH][TB];  // 128 KB
  __shared__ float sq[2][BNE][TB];   // trits as float, 8 KB
  __shared__ float sx[FIN][TB];      // staged x_t, 2 KB
  __shared__ float sout[TB][OUTD];   // dense output (AR feedback)

  const int t  = threadIdx.x;          // 0..1023
  const int b0 = blockIdx.x * TB;

  for (int i = t; i < HH * TB; i += NTHR) {
    (&sh0[0][0])[i] = 0.f; (&sc0[0][0])[i] = 0.f;
    (&sh1[0][0])[i] = 0.f; (&sc1[0][0])[i] = 0.f;
  }

  // ---- matmul mapping (r6 verbatim, 4 sample-blocks): thread owns units {2q,2q+1},
  //      all 4 gates, samples [4v, 4v+4) ----
  const int q  = t & 255;              // unit-pair index
  const int v  = t >> 8;               // sample block 0..3
  const int s4 = 4 * v;
  const int u0 = 2 * q;
  float2 bg0[4], bg1[4];
#pragma unroll
  for (int m = 0; m < 4; m++) {
    const int c = m * HH + u0;
    bg0[m] = make_float2(bih0[c] + bhh0[c], bih0[c + 1] + bhh0[c + 1]);
    bg1[m] = make_float2(bih1[c] + bhh1[c], bih1[c + 1] + bhh1[c + 1]);
  }

  // ---- encoder mapping: (n, sample); each thread runs BOTH AE chains for (n,sE) ----
  const int n = t & 63, sE = t >> 6;   // sE 0..15

  // ---- decoder mapping: col t of Wd (h-part if t<512, else c-part) ----
  const float bdv = bd[t];

  const double Athr = 0.5493061443340549;  // atanh(0.5)

  for (int step = 0; step < TOT; ++step) {
    __syncthreads();

    // ================= A: AE encoders (fp64, exact chain order, both AEs/thread) ====
    {
      double a0 = (double)be[n], a1 = a0;
      const float* weh = We + n;
#pragma unroll 4
      for (int k = 0; k < HH; k++) {
        const double wv = (double)weh[(size_t)k * BNE];
        a0 = fma((double)sh0[k][sE], wv, a0);
        a1 = fma((double)sh1[k][sE], wv, a1);
      }
      const float* wec = We + (size_t)HH * BNE + n;
#pragma unroll 4
      for (int k = 0; k < HH; k++) {
        const double wv = (double)wec[(size_t)k * BNE];
        a0 = fma((double)sc0[k][sE], wv, a0);
        a1 = fma((double)sc1[k][sE], wv, a1);
      }
      sq[0][n][sE] = (a0 > Athr) ? 1.f : ((a0 < -Athr) ? -1.f : 0.f);
      sq[1][n][sE] = (a1 > Athr) ? 1.f : ((a1 < -Athr) ? -1.f : 0.f);
    }
    __syncthreads();

    // ================= B: AE decode (1 col/thread, 16 samples, AEs sequential) ======
    {
      const float* wd = Wd + t;
      float d[TB];
      // ---- AE 0 ----
#pragma unroll
      for (int s = 0; s < TB; s++) d[s] = bdv;
#pragma unroll 2
      for (int j = 0; j < BNE; j++) {
        const float w = wd[(size_t)j * (2 * HH)];
        const float4 qA = *(const float4*)&sq[0][j][0];
        const float4 qB = *(const float4*)&sq[0][j][4];
        const float4 qC = *(const float4*)&sq[0][j][8];
        const float4 qD = *(const float4*)&sq[0][j][12];
        d[0]  = fmaf(qA.x, w, d[0]);  d[1]  = fmaf(qA.y, w, d[1]);
        d[2]  = fmaf(qA.z, w, d[2]);  d[3]  = fmaf(qA.w, w, d[3]);
        d[4]  = fmaf(qB.x, w, d[4]);  d[5]  = fmaf(qB.y, w, d[5]);
        d[6]  = fmaf(qB.z, w, d[6]);  d[7]  = fmaf(qB.w, w, d[7]);
        d[8]  = fmaf(qC.x, w, d[8]);  d[9]  = fmaf(qC.y, w, d[9]);
        d[10] = fmaf(qC.z, w, d[10]); d[11] = fmaf(qC.w, w, d[11]);
        d[12] = fmaf(qD.x, w, d[12]); d[13] = fmaf(qD.y, w, d[13]);
        d[14] = fmaf(qD.z, w, d[14]); d[15] = fmaf(qD.w, w, d[15]);
      }
      {
        float* dst = (t < HH) ? &sh0[t][0] : &sc0[t - HH][0];
#pragma unroll
        for (int s = 0; s < TB; s += 4)
          *(float4*)&dst[s] = make_float4(d[s], d[s+1], d[s+2], d[s+3]);
      }
      // ---- AE 1 ----
#pragma unroll
      for (int s = 0; s < TB; s++) d[s] = bdv;
#pragma unroll 2
      for (int j = 0; j < BNE; j++) {
        const float w = wd[(size_t)j * (2 * HH)];
        const float4 qA = *(const float4*)&sq[1][j][0];
        const float4 qB = *(const float4*)&sq[1][j][4];
        const float4 qC = *(const float4*)&sq[1][j][8];
        const float4 qD = *(const float4*)&sq[1][j][12];
        d[0]  = fmaf(qA.x, w, d[0]);  d[1]  = fmaf(qA.y, w, d[1]);
        d[2]  = fmaf(qA.z, w, d[2]);  d[3]  = fmaf(qA.w, w, d[3]);
        d[4]  = fmaf(qB.x, w, d[4]);  d[5]  = fmaf(qB.y, w, d[5]);
        d[6]  = fmaf(qB.z, w, d[6]);  d[7]  = fmaf(qB.w, w, d[7]);
        d[8]  = fmaf(qC.x, w, d[8]);  d[9]  = fmaf(qC.y, w, d[9]);
        d[10] = fmaf(qC.z, w, d[10]); d[11] = fmaf(qC.w, w, d[11]);
        d[12] = fmaf(qD.x, w, d[12]); d[13] = fmaf(qD.y, w, d[13]);
        d[14] = fmaf(qD.z, w, d[14]); d[15] = fmaf(qD.w, w, d[15]);
      }
      {
        float* dst = (t < HH) ? &sh1[t][0] : &sc1[t - HH][0];
#pragma unroll
        for (int s = 0; s < TB; s += 4)
          *(float4*)&dst[s] = make_float4(d[s], d[s+1], d[s+2], d[s+3]);
      }
      if (t < FIN * TB) {        // 512 threads stage x_t (with AR feedback)
        int s = t >> 5, f = t & 31;
        float xv;
        if (step >= SEQL && f < OUTD) xv = sout[s][f];
        else xv = x[((size_t)(b0 + s) * TOT + step) * FIN + f];
        sx[f][s] = xv;
      }
    }
    __syncthreads();

    // ================= C: layer-0 LSTM (r6 verbatim per-thread body) =================
    {
      float2 gI[4], gF[4], gG[4], gO[4];
#pragma unroll
      for (int i = 0; i < 4; i++) { gI[i] = bg0[0]; gF[i] = bg0[1]; gG[i] = bg0[2]; gO[i] = bg0[3]; }
      {
        const float* row = Wih0 + u0;
#pragma unroll 4
        for (int k = 0; k < FIN; k++, row += G4) {
          const float2 wI = *(const float2*)(row);
          const float2 wF = *(const float2*)(row + HH);
          const float2 wG = *(const float2*)(row + 2 * HH);
          const float2 wO = *(const float2*)(row + 3 * HH);
          const float4 hv = *(const float4*)&sx[k][s4];
          GMAC4(gI, wI); GMAC4(gF, wF); GMAC4(gG, wG); GMAC4(gO, wO);
        }
      }
      {
        const float* row = Whh0 + u0;
#pragma unroll 8
        for (int k = 0; k < HH; k++, row += G4) {
          const float2 wI = *(const float2*)(row);
          const float2 wF = *(const float2*)(row + HH);
          const float2 wG = *(const float2*)(row + 2 * HH);
          const float2 wO = *(const float2*)(row + 3 * HH);
          const float4 hv = *(const float4*)&sh0[k][s4];
          GMAC4(gI, wI); GMAC4(gF, wF); GMAC4(gG, wG); GMAC4(gO, wO);
        }
      }
      const float4 cA = *(const float4*)&sc0[u0][s4];
      const float4 cB = *(const float4*)&sc0[u0 + 1][s4];
      const float coldA[4] = { cA.x, cA.y, cA.z, cA.w };
      const float coldB[4] = { cB.x, cB.y, cB.z, cB.w };
      float4 hnA, hnB, cnA, cnB;
      float* hA = (float*)&hnA; float* hB = (float*)&hnB;
      float* cnAp = (float*)&cnA; float* cnBp = (float*)&cnB;
#pragma unroll
      for (int i = 0; i < 4; i++) {
        float ig = sigf(gI[i].x), fg = sigf(gF[i].x);
        float gt = tanhf(gG[i].x), og = sigf(gO[i].x);
        float c2 = fmaf(fg, coldA[i], ig * gt);
        cnAp[i] = c2; hA[i] = og * tanhf(c2);
        ig = sigf(gI[i].y); fg = sigf(gF[i].y);
        gt = tanhf(gG[i].y); og = sigf(gO[i].y);
        c2 = fmaf(fg, coldB[i], ig * gt);
        cnBp[i] = c2; hB[i] = og * tanhf(c2);
      }
      __syncthreads();   // all K-loop reads of decoded sh0 done before overwrite
      *(float4*)&sh0[u0][s4]     = hnA;
      *(float4*)&sh0[u0 + 1][s4] = hnB;
      *(float4*)&sc0[u0][s4]     = cnA;
      *(float4*)&sc0[u0 + 1][s4] = cnB;
    }
    __syncthreads();

    // ================= D: layer-1 LSTM =================
    {
      float2 gI[4], gF[4], gG[4], gO[4];
#pragma unroll
      for (int i = 0; i < 4; i++) { gI[i] = bg1[0]; gF[i] = bg1[1]; gG[i] = bg1[2]; gO[i] = bg1[3]; }
      {
        const float* row = Wih1 + u0;
#pragma unroll 8
        for (int k = 0; k < HH; k++, row += G4) {
          const float2 wI = *(const float2*)(row);
          const float2 wF = *(const float2*)(row + HH);
          const float2 wG = *(const float2*)(row + 2 * HH);
          const float2 wO = *(const float2*)(row + 3 * HH);
          const float4 hv = *(const float4*)&sh0[k][s4];   // new h0
          GMAC4(gI, wI); GMAC4(gF, wF); GMAC4(gG, wG); GMAC4(gO, wO);
        }
      }
      {
        const float* row = Whh1 + u0;
#pragma unroll 8
        for (int k = 0; k < HH; k++, row += G4) {
          const float2 wI = *(const float2*)(row);
          const float2 wF = *(const float2*)(row + HH);
          const float2 wG = *(const float2*)(row + 2 * HH);
          const float2 wO = *(const float2*)(row + 3 * HH);
          const float4 hv = *(const float4*)&sh1[k][s4];   // decoded h1
          GMAC4(gI, wI); GMAC4(gF, wF); GMAC4(gG, wG); GMAC4(gO, wO);
        }
      }
      const float4 cA = *(const float4*)&sc1[u0][s4];
      const float4 cB = *(const float4*)&sc1[u0 + 1][s4];
      const float coldA[4] = { cA.x, cA.y, cA.z, cA.w };
      const float coldB[4] = { cB.x, cB.y, cB.z, cB.w };
      float4 hnA, hnB, cnA, cnB;
      float* hA = (float*)&hnA; float* hB = (float*)&hnB;
      float* cnAp = (float*)&cnA; float* cnBp = (float*)&cnB;
#pragma unroll
      for (int i = 0; i < 4; i++) {
        float ig = sigf(gI[i].x), fg = sigf(gF[i].x);
        float gt = tanhf(gG[i].x), og = sigf(gO[i].x);
        float c2 = fmaf(fg, coldA[i], ig * gt);
        cnAp[i] = c2; hA[i] = og * tanhf(c2);
        ig = sigf(gI[i].y); fg = sigf(gF[i].y);
        gt = tanhf(gG[i].y); og = sigf(gO[i].y);
        c2 = fmaf(fg, coldB[i], ig * gt);
        cnBp[i] = c2; hB[i] = og * tanhf(c2);
      }
      __syncthreads();   // all K-loop reads of sh1 done before overwrite
      *(float4*)&sh1[u0][s4]     = hnA;
      *(float4*)&sh1[u0 + 1][s4] = hnB;
      *(float4*)&sc1[u0][s4]     = cnA;
      *(float4*)&sc1[u0 + 1][s4] = cnB;
    }

    // ================= E: final dense =================
    if (step >= SEQL - 1) {
      __syncthreads();  // new sh1 visible
      if (t < TB * OUTD) {
        int s = t >> 3, o = t & 7;
        float a = bf[o];
#pragma unroll 4
        for (int k = 0; k < HH; k++) a = fmaf(sh1[k][s], Wf[k * OUTD + o], a);
        sout[s][o] = a;
        int slot = step - (SEQL - 1);
        out[((size_t)(b0 + s) * (1 + LOOK) + slot) * OUTD + o] = a;
      }
    }
  }
}

extern "C" void kernel_launch(void* const* d_in, const int* in_sizes, int n_in,
                              void* d_out, int out_size, void* d_ws, size_t ws_size,
                              hipStream_t stream) {
  const float* x    = (const float*)d_in[0];
  const float* Wih0 = (const float*)d_in[1];
  const float* Whh0 = (const float*)d_in[2];
  const float* bih0 = (const float*)d_in[3];
  const float* bhh0 = (const float*)d_in[4];
  const float* Wih1 = (const float*)d_in[5];
  const float* Whh1 = (const float*)d_in[6];
  const float* bih1 = (const float*)d_in[7];
  const float* bhh1 = (const float*)d_in[8];
  const float* We   = (const float*)d_in[9];
  const float* be   = (const float*)d_in[10];
  const float* Wd   = (const float*)d_in[11];
  const float* bd   = (const float*)d_in[12];
  const float* Wf   = (const float*)d_in[13];
  const float* bf   = (const float*)d_in[14];

  fused_rnn<<<NB / TB, NTHR, 0, stream>>>(x, Wih0, Whh0, bih0, bhh0,
                                          Wih1, Whh1, bih1, bhh1,
                                          We, be, Wd, bd, Wf, bf,
                                          (float*)d_out);
}

// Round 13
// 79932.544 us; speedup vs baseline: 1.6062x; 1.6062x over previous
//
#include <hip/hip_runtime.h>
#include <math.h>

#define NB    2048
#define FIN   32
#define HH    512
#define G4    2048           // 4*H
#define BNE   64
#define OUTD  8
#define SEQL  128
#define LOOK  32
#define TOT   (SEQL + LOOK)
#define TB    8              // samples per workgroup
#define NTHR  512

__device__ __forceinline__ float sigf(float v) { return 1.0f / (1.0f + expf(-v)); }

// acc[S] (float4 over 4 cols) += w * state_scalar
#define FMA4S(W, HS, S)                                 \
  { acc[S].x = fmaf((W).x, (HS), acc[S].x);             \
    acc[S].y = fmaf((W).y, (HS), acc[S].y);             \
    acc[S].z = fmaf((W).z, (HS), acc[S].z);             \
    acc[S].w = fmaf((W).w, (HS), acc[S].w); }

// one k-row: 4 cols x 8 samples = 32 FMAs
#define FMAROW(W, K, STATE)                             \
  { const float4 hA = *(const float4*)&STATE[K][0];     \
    const float4 hB = *(const float4*)&STATE[K][4];     \
    FMA4S(W, hA.x, 0) FMA4S(W, hA.y, 1)                 \
    FMA4S(W, hA.z, 2) FMA4S(W, hA.w, 3)                 \
    FMA4S(W, hB.x, 4) FMA4S(W, hB.y, 5)                 \
    FMA4S(W, hB.z, 6) FMA4S(W, hB.w, 7) }

// issue 8 weight rows (float4 each) of block KB
#define LOADBLK(DST, WP, KB)                            \
  { _Pragma("unroll")                                   \
    for (int i = 0; i < 8; i++)                         \
      DST[i] = (WP)[((KB) * 8 + i) * (G4 / 4)]; }

// consume block KB (8 rows)
#define FMABLK(SRC, KB, STATE)                          \
  { _Pragma("unroll")                                   \
    for (int i = 0; i < 8; i++) { FMAROW(SRC[i], (KB) * 8 + i, STATE) } }

// K=512: 64 blocks, two-block rolling pipeline (8 float4 loads always in flight)
#define K512_PIPE(WPTR, STATE)                          \
  { const float4* wp = (const float4*)(WPTR) + t;       \
    float4 wa[8], wb[8];                                \
    LOADBLK(wa, wp, 0)                                  \
    _Pragma("unroll 1")                                 \
    for (int kb = 0; kb < 31; kb++) {                   \
      LOADBLK(wb, wp, 2 * kb + 1)                       \
      FMABLK(wa, 2 * kb, STATE)                         \
      LOADBLK(wa, wp, 2 * kb + 2)                       \
      FMABLK(wb, 2 * kb + 1, STATE)                     \
    }                                                   \
    LOADBLK(wb, wp, 63)                                 \
    FMABLK(wa, 62, STATE)                               \
    FMABLK(wb, 63, STATE) }

__global__ __launch_bounds__(NTHR, 2)
void fused_rnn(const float* __restrict__ x,
               const float* __restrict__ Wih0, const float* __restrict__ Whh0,
               const float* __restrict__ bih0, const float* __restrict__ bhh0,
               const float* __restrict__ Wih1, const float* __restrict__ Whh1,
               const float* __restrict__ bih1, const float* __restrict__ bhh1,
               const float* __restrict__ We,   const float* __restrict__ be,
               const float* __restrict__ Wd,   const float* __restrict__ bd,
               const float* __restrict__ Wf,   const float* __restrict__ bf,
               float* __restrict__ out)
{
  // states [unit][sample]: fixed-k access is a wave-uniform b128 broadcast
  __shared__ float sh0[HH][TB], sc0[HH][TB], sh1[HH][TB], sc1[HH][TB];  // 64 KB
  __shared__ float sg[TB][G4];       // gate pre-activations [sample][col], 64 KB
  __shared__ float tq[2][BNE][TB];   // trits as float, 4 KB
  __shared__ float sx[FIN][TB];      // staged x_t, 1 KB
  __shared__ float sout[TB][OUTD];   // dense output (AR feedback)

  const int t  = threadIdx.x;          // 0..511
  const int b0 = blockIdx.x * TB;

  for (int i = t; i < HH * TB; i += NTHR) {
    (&sh0[0][0])[i] = 0.f; (&sc0[0][0])[i] = 0.f;
    (&sh1[0][0])[i] = 0.f; (&sc1[0][0])[i] = 0.f;
  }

  // matmul mapping: thread owns 4 contiguous gate cols [4t, 4t+4), all 8 samples
  float4 bg0, bg1;
  { const float4 a = *(const float4*)&bih0[4 * t];
    const float4 b = *(const float4*)&bhh0[4 * t];
    bg0 = make_float4(a.x + b.x, a.y + b.y, a.z + b.z, a.w + b.w); }
  { const float4 a = *(const float4*)&bih1[4 * t];
    const float4 b = *(const float4*)&bhh1[4 * t];
    bg1 = make_float4(a.x + b.x, a.y + b.y, a.z + b.z, a.w + b.w); }

  // encoder mapping (r2 verbatim): (ae, n, sample-pair)
  const int ae = t >> 8, n = t & 63, sp = (t >> 6) & 3;

  const double Athr = 0.5493061443340549;  // atanh(0.5)

  for (int step = 0; step < TOT; ++step) {
    __syncthreads();

    // ================= A: AE encoders (r2 verbatim: fp64, 2 samples/thread) ========
    {
      const float* Sh = ae ? &sh1[0][0] : &sh0[0][0];
      const float* Sc = ae ? &sc1[0][0] : &sc0[0][0];
      double a0 = (double)be[n], a1 = a0;
      const float* weh = We + n;
#pragma unroll 4
      for (int k = 0; k < HH; k++) {
        const float2 zz = *(const float2*)&Sh[k * TB + 2 * sp];
        const double wv = (double)weh[(size_t)k * BNE];
        a0 = fma((double)zz.x, wv, a0);
        a1 = fma((double)zz.y, wv, a1);
      }
      const float* wec = We + (size_t)HH * BNE + n;
#pragma unroll 4
      for (int k = 0; k < HH; k++) {
        const float2 zz = *(const float2*)&Sc[k * TB + 2 * sp];
        const double wv = (double)wec[(size_t)k * BNE];
        a0 = fma((double)zz.x, wv, a0);
        a1 = fma((double)zz.y, wv, a1);
      }
      tq[ae][n][2 * sp]     = (a0 > Athr) ? 1.f : ((a0 < -Athr) ? -1.f : 0.f);
      tq[ae][n][2 * sp + 1] = (a1 > Athr) ? 1.f : ((a1 < -Athr) ? -1.f : 0.f);
    }
    __syncthreads();

    // ================= B: AE decode (r2 verbatim: col t h-part + col 512+t c-part) ==
    {
      float aq0[TB], aq1[TB], ac0[TB], ac1[TB];
      const float bdh = bd[t], bdc = bd[HH + t];
#pragma unroll
      for (int s = 0; s < TB; s++) { aq0[s] = bdh; ac0[s] = bdc; aq1[s] = bdh; ac1[s] = bdc; }
      const float* wd0 = Wd + t;            // h-part col t
      const float* wd1 = Wd + HH + t;       // c-part col 512+t
#pragma unroll 2
      for (int j = 0; j < BNE; j++) {
        const float w0 = wd0[(size_t)j * (2 * HH)];
        const float w1 = wd1[(size_t)j * (2 * HH)];
        const float4 qA0 = *(const float4*)&tq[0][j][0];
        const float4 qB0 = *(const float4*)&tq[0][j][4];
        const float4 qA1 = *(const float4*)&tq[1][j][0];
        const float4 qB1 = *(const float4*)&tq[1][j][4];
        aq0[0] = fmaf(qA0.x, w0, aq0[0]); ac0[0] = fmaf(qA0.x, w1, ac0[0]);
        aq0[1] = fmaf(qA0.y, w0, aq0[1]); ac0[1] = fmaf(qA0.y, w1, ac0[1]);
        aq0[2] = fmaf(qA0.z, w0, aq0[2]); ac0[2] = fmaf(qA0.z, w1, ac0[2]);
        aq0[3] = fmaf(qA0.w, w0, aq0[3]); ac0[3] = fmaf(qA0.w, w1, ac0[3]);
        aq0[4] = fmaf(qB0.x, w0, aq0[4]); ac0[4] = fmaf(qB0.x, w1, ac0[4]);
        aq0[5] = fmaf(qB0.y, w0, aq0[5]); ac0[5] = fmaf(qB0.y, w1, ac0[5]);
        aq0[6] = fmaf(qB0.z, w0, aq0[6]); ac0[6] = fmaf(qB0.z, w1, ac0[6]);
        aq0[7] = fmaf(qB0.w, w0, aq0[7]); ac0[7] = fmaf(qB0.w, w1, ac0[7]);
        aq1[0] = fmaf(qA1.x, w0, aq1[0]); ac1[0] = fmaf(qA1.x, w1, ac1[0]);
        aq1[1] = fmaf(qA1.y, w0, aq1[1]); ac1[1] = fmaf(qA1.y, w1, ac1[1]);
        aq1[2] = fmaf(qA1.z, w0, aq1[2]); ac1[2] = fmaf(qA1.z, w1, ac1[2]);
        aq1[3] = fmaf(qA1.w, w0, aq1[3]); ac1[3] = fmaf(qA1.w, w1, ac1[3]);
        aq1[4] = fmaf(qB1.x, w0, aq1[4]); ac1[4] = fmaf(qB1.x, w1, ac1[4]);
        aq1[5] = fmaf(qB1.y, w0, aq1[5]); ac1[5] = fmaf(qB1.y, w1, ac1[5]);
        aq1[6] = fmaf(qB1.z, w0, aq1[6]); ac1[6] = fmaf(qB1.z, w1, ac1[6]);
        aq1[7] = fmaf(qB1.w, w0, aq1[7]); ac1[7] = fmaf(qB1.w, w1, ac1[7]);
      }
#pragma unroll
      for (int s = 0; s < TB; s++) {
        sh0[t][s] = aq0[s]; sc0[t][s] = ac0[s];
        sh1[t][s] = aq1[s]; sc1[t][s] = ac1[s];
      }
      if (t < FIN * TB) {        // stage x_t (with AR feedback)
        int s = t >> 5, f = t & 31;
        float xv;
        if (step >= SEQL && f < OUTD) xv = sout[s][f];
        else xv = x[((size_t)(b0 + s) * TOT + step) * FIN + f];
        sx[f][s] = xv;
      }
    }
    __syncthreads();

    // ================= C: layer-0 matmul (pipelined float4 weights) ================
    {
      float4 acc[TB];
#pragma unroll
      for (int s = 0; s < TB; s++) acc[s] = bg0;
      { // x part, K=32: 4 blocks
        const float4* wp = (const float4*)Wih0 + t;
        float4 wa[8], wb[8];
        LOADBLK(wa, wp, 0)
        LOADBLK(wb, wp, 1)
        FMABLK(wa, 0, sx)
        LOADBLK(wa, wp, 2)
        FMABLK(wb, 1, sx)
        LOADBLK(wb, wp, 3)
        FMABLK(wa, 2, sx)
        FMABLK(wb, 3, sx)
      }
      K512_PIPE(Whh0, sh0)
#pragma unroll
      for (int s = 0; s < TB; s++) *(float4*)&sg[s][4 * t] = acc[s];
    }
    __syncthreads();
    // layer-0 elementwise: thread = unit t, all 8 samples
    {
#pragma unroll 2
      for (int s = 0; s < TB; s++) {
        const float ig = sigf(sg[s][t]);
        const float fg = sigf(sg[s][HH + t]);
        const float gt = tanhf(sg[s][2 * HH + t]);
        const float og = sigf(sg[s][3 * HH + t]);
        const float c2 = fmaf(fg, sc0[t][s], ig * gt);
        sc0[t][s] = c2;
        sh0[t][s] = og * tanhf(c2);
      }
    }
    __syncthreads();

    // ================= D: layer-1 matmul =================
    {
      float4 acc[TB];
#pragma unroll
      for (int s = 0; s < TB; s++) acc[s] = bg1;
      K512_PIPE(Wih1, sh0)    // input = new h0
      K512_PIPE(Whh1, sh1)    // recurrent = decoded h1
#pragma unroll
      for (int s = 0; s < TB; s++) *(float4*)&sg[s][4 * t] = acc[s];
    }
    __syncthreads();
    // layer-1 elementwise
    {
#pragma unroll 2
      for (int s = 0; s < TB; s++) {
        const float ig = sigf(sg[s][t]);
        const float fg = sigf(sg[s][HH + t]);
        const float gt = tanhf(sg[s][2 * HH + t]);
        const float og = sigf(sg[s][3 * HH + t]);
        const float c2 = fmaf(fg, sc1[t][s], ig * gt);
        sc1[t][s] = c2;
        sh1[t][s] = og * tanhf(c2);
      }
    }

    // ================= E: final dense (r2 verbatim) =================
    if (step >= SEQL - 1) {
      __syncthreads();  // new sh1 visible
      if (t < TB * OUTD) {
        int s = t >> 3, o = t & 7;
        float a = bf[o];
#pragma unroll 4
        for (int k = 0; k < HH; k++) a = fmaf(sh1[k][s], Wf[k * OUTD + o], a);
        sout[s][o] = a;
        int slot = step - (SEQL - 1);
        out[((size_t)(b0 + s) * (1 + LOOK) + slot) * OUTD + o] = a;
      }
    }
  }
}

extern "C" void kernel_launch(void* const* d_in, const int* in_sizes, int n_in,
                              void* d_out, int out_size, void* d_ws, size_t ws_size,
                              hipStream_t stream) {
  const float* x    = (const float*)d_in[0];
  const float* Wih0 = (const float*)d_in[1];
  const float* Whh0 = (const float*)d_in[2];
  const float* bih0 = (const float*)d_in[3];
  const float* bhh0 = (const float*)d_in[4];
  const float* Wih1 = (const float*)d_in[5];
  const float* Whh1 = (const float*)d_in[6];
  const float* bih1 = (const float*)d_in[7];
  const float* bhh1 = (const float*)d_in[8];
  const float* We   = (const float*)d_in[9];
  const float* be   = (const float*)d_in[10];
  const float* Wd   = (const float*)d_in[11];
  const float* bd   = (const float*)d_in[12];
  const float* Wf   = (const float*)d_in[13];
  const float* bf   = (const float*)d_in[14];

  fused_rnn<<<NB / TB, NTHR, 0, stream>>>(x, Wih0, Whh0, bih0, bhh0,
                                          Wih1, Whh1, bih1, bhh1,
                                          We, be, Wd, bd, Wf, bf,
                                          (float*)d_out);
}